// Round 1
// baseline (190.426 us; speedup 1.0000x reference)
//
#include <hip/hip_runtime.h>
#include <math.h>

#define THREADS 256
#define BIG_BLOCKS 2048

// ---- monotone float <-> uint encoding (order-preserving) ----
__device__ __forceinline__ unsigned enc_f(float f) {
    unsigned b = __float_as_uint(f);
    return (b & 0x80000000u) ? ~b : (b | 0x80000000u);
}
__device__ __forceinline__ float dec_f(unsigned u) {
    unsigned b = (u & 0x80000000u) ? (u ^ 0x80000000u) : ~u;
    return __uint_as_float(b);
}

#define ENC_NEG_INF 0x007FFFFFu   // enc(-inf): identity for max
#define ENC_POS_INF 0xFF800000u   // enc(+inf): identity for min

// ws layout (as unsigned*):
//   [0..7]   gmax  (max-acc)
//   [8..15]  pmin  (min-acc)
//   [16..23] zmin  (min-acc)
//   [24..31] zmax  (max-acc)
//   [32..33] double loss accumulator (128-byte offset, 8B aligned)

__global__ void k_init(unsigned* __restrict__ ws) {
    int t = threadIdx.x;
    if (t < 32) ws[t] = (t < 8 || t >= 24) ? ENC_NEG_INF : ENC_POS_INF;
    if (t == 0) *(double*)(ws + 32) = 0.0;
}

__global__ __launch_bounds__(THREADS) void k_stats(
        const float* __restrict__ coord, const int* __restrict__ segment,
        const int* __restrict__ offset, unsigned* __restrict__ ws,
        int n, int nb) {
    __shared__ unsigned s_stats[32];  // [stat][batch]: 0 gmax, 1 pmin, 2 zmin, 3 zmax
    __shared__ int s_off[8];
    const int tid = threadIdx.x;
    if (tid < 32) s_stats[tid] = (tid < 8 || tid >= 24) ? ENC_NEG_INF : ENC_POS_INF;
    if (tid < 8)  s_off[tid] = (tid < nb) ? offset[tid] : 0x7FFFFFFF;
    __syncthreads();

    const int chunk = (n + gridDim.x - 1) / gridDim.x;
    const int start = blockIdx.x * chunk;
    const int end   = min(n, start + chunk);

    int curb = -1;
    float lg = -INFINITY, lp = INFINITY, lmn = INFINITY, lmx = -INFINITY;

    for (int i = start + tid; i < end; i += blockDim.x) {
        float z = coord[3 * i + 2];
        int   s = segment[i];
        int b = 0;
        #pragma unroll
        for (int j = 0; j < 8; ++j) b += (i >= s_off[j]);
        if (b != curb) {
            if (curb >= 0) {
                atomicMax(&s_stats[0 * 8 + curb], enc_f(lg));
                atomicMin(&s_stats[1 * 8 + curb], enc_f(lp));
                atomicMin(&s_stats[2 * 8 + curb], enc_f(lmn));
                atomicMax(&s_stats[3 * 8 + curb], enc_f(lmx));
            }
            lg = -INFINITY; lp = INFINITY; lmn = INFINITY; lmx = -INFINITY;
            curb = b;
        }
        lmn = fminf(lmn, z);
        lmx = fmaxf(lmx, z);
        if (s == 0) lg = fmaxf(lg, z);
        else        lp = fminf(lp, z);
    }
    if (curb >= 0) {
        atomicMax(&s_stats[0 * 8 + curb], enc_f(lg));
        atomicMin(&s_stats[1 * 8 + curb], enc_f(lp));
        atomicMin(&s_stats[2 * 8 + curb], enc_f(lmn));
        atomicMax(&s_stats[3 * 8 + curb], enc_f(lmx));
    }
    __syncthreads();

    if (tid < 32) {
        unsigned v = s_stats[tid];
        unsigned ident = (tid < 8 || tid >= 24) ? ENC_NEG_INF : ENC_POS_INF;
        if (v != ident) {
            if (tid < 8)       atomicMax(&ws[tid], v);
            else if (tid < 24) atomicMin(&ws[tid], v);
            else               atomicMax(&ws[tid], v);
        }
    }
}

__global__ __launch_bounds__(THREADS) void k_loss(
        const float* __restrict__ pred, const float* __restrict__ coord,
        const int* __restrict__ segment, const int* __restrict__ offset,
        const unsigned* __restrict__ ws, double* __restrict__ acc,
        int n, int nb) {
    __shared__ float s_mu[8];
    __shared__ int   s_off[8];
    __shared__ float s_part[THREADS / 64];
    const int tid = threadIdx.x;

    if (tid < 8) {
        s_off[tid] = (tid < nb) ? offset[tid] : 0x7FFFFFFF;
        unsigned ug = ws[tid], up = ws[8 + tid];
        float g   = dec_f(ug);
        float p   = dec_f(up);
        float zmn = dec_f(ws[16 + tid]);
        float zmx = dec_f(ws[24 + tid]);
        if (ug == ENC_NEG_INF) g = zmn;   // no ground points -> fallback z.min
        if (up == ENC_POS_INF) p = zmx;   // no plant points  -> fallback z.max
        s_mu[tid] = g + (p - g) * 0.5f;
    }
    __syncthreads();

    const int chunk = (n + gridDim.x - 1) / gridDim.x;
    const int start = blockIdx.x * chunk;
    const int end   = min(n, start + chunk);
    const float2* pred2 = (const float2*)pred;

    float lsum = 0.0f;
    for (int i = start + tid; i < end; i += blockDim.x) {
        float2 pr = pred2[i];
        float z = coord[3 * i + 2];
        int   s = segment[i];
        int b = 0;
        #pragma unroll
        for (int j = 0; j < 8; ++j) b += (i >= s_off[j]);
        float mu = s_mu[b];

        // log-softmax over 2 classes (max-subtracted, matches XLA form)
        float p0 = pr.x, p1 = pr.y;
        float m   = fmaxf(p0, p1);
        float lse = m + logf(expf(p0 - m) + expf(p1 - m));
        float logp_t = ((s == 0) ? p0 : p1) - lse;
        float p_t = expf(logp_t);
        float om  = 1.0f - p_t;
        float loss = -logp_t * om * om;  // LOSS_WEIGHT=1, FOCAL_ALPHA=1, gamma=2

        // asymmetric gaussian z-weighting
        float d  = z - mu;
        float d2 = d * d;
        float w = (z <= mu) ? expf(-d2 * 50.0f)                        // 1/(2*0.1^2)
                            : ((d > 0.8f) ? 0.1f                        // 2.0*0.4
                                          : expf(-d2 * 3.125f));        // 1/(2*0.4^2)
        lsum += loss * w;
    }

    // wave (64) shuffle reduction
    #pragma unroll
    for (int off = 32; off > 0; off >>= 1)
        lsum += __shfl_down(lsum, off, 64);
    const int wave = tid >> 6, lane = tid & 63;
    if (lane == 0) s_part[wave] = lsum;
    __syncthreads();
    if (tid == 0) {
        float t = 0.0f;
        #pragma unroll
        for (int wv = 0; wv < THREADS / 64; ++wv) t += s_part[wv];
        atomicAdd(acc, (double)t);
    }
}

__global__ void k_final(const double* __restrict__ acc, float* __restrict__ out, int n) {
    out[0] = (float)(acc[0] / (double)n);
}

extern "C" void kernel_launch(void* const* d_in, const int* in_sizes, int n_in,
                              void* d_out, int out_size, void* d_ws, size_t ws_size,
                              hipStream_t stream) {
    const float* pred    = (const float*)d_in[0];
    const float* coord   = (const float*)d_in[1];
    const int*   segment = (const int*)d_in[2];
    const int*   offset  = (const int*)d_in[3];
    const int n  = in_sizes[2];
    const int nb = in_sizes[3];

    unsigned* ws  = (unsigned*)d_ws;
    double*   acc = (double*)(ws + 32);

    hipLaunchKernelGGL(k_init,  dim3(1), dim3(64), 0, stream, ws);
    hipLaunchKernelGGL(k_stats, dim3(BIG_BLOCKS), dim3(THREADS), 0, stream,
                       coord, segment, offset, ws, n, nb);
    hipLaunchKernelGGL(k_loss,  dim3(BIG_BLOCKS), dim3(THREADS), 0, stream,
                       pred, coord, segment, offset, ws, acc, n, nb);
    hipLaunchKernelGGL(k_final, dim3(1), dim3(1), 0, stream, acc, (float*)d_out, n);
}